// Round 13
// baseline (274.356 us; speedup 1.0000x reference)
//
#include <hip/hip_runtime.h>
#include <hip/hip_bf16.h>

// Problem constants: B=4, N=4096, C=1024, H=16, d=64
#define BB 4
#define NN 4096
#define CC 1024
#define HH 16
#define MM (BB*NN)
#define EPSF 1e-6f

typedef _Float16 f16x8 __attribute__((ext_vector_type(8)));
typedef float f32x4 __attribute__((ext_vector_type(4)));

__device__ __forceinline__ void gload_lds16(const void* g, void* l) {
    __builtin_amdgcn_global_load_lds(
        (const __attribute__((address_space(1))) void*)g,
        (__attribute__((address_space(3))) void*)l, 16, 0, 0);
}

// ---------------------------------------------------------------------------
__global__ __launch_bounds__(256)
void tofp16_all(const float* __restrict__ x, const float* __restrict__ wq,
                const float* __restrict__ wp, _Float16* __restrict__ xf,
                _Float16* __restrict__ wqf, _Float16* __restrict__ wpf)
{
    int i = blockIdx.x * 256 + threadIdx.x;
    const float* src; _Float16* dst; int off;
    if (i < 4194304)      { src = x;  dst = xf;  off = 0; }
    else if (i < 4980736) { src = wq; dst = wqf; off = 4194304; }
    else                  { src = wp; dst = wpf; off = 4980736; }
    int j = i - off;
    float4 f = ((const float4*)src)[j];
    short4 pk;
    pk.x = __builtin_bit_cast(short, (_Float16)f.x);
    pk.y = __builtin_bit_cast(short, (_Float16)f.y);
    pk.z = __builtin_bit_cast(short, (_Float16)f.z);
    pk.w = __builtin_bit_cast(short, (_Float16)f.w);
    ((short4*)dst)[j] = pk;
}

// ---------------------------------------------------------------------------
// 256x256-tile fp16 MFMA GEMM, BK=32, 8 waves (2Mx4N), 16x16x32 MFMA.
// A staged via 3 LDS buffers (16KB each, A ONLY), stage-2-ahead.
// B-fragments loaded DIRECT from global (L2-hot weights) into registers,
// prefetched one K-tile ahead (bb0/bb1 double-register).  This cuts per-CU
// LDS traffic from 128KB to 80KB per K-tile (diagnosed LDS-BW serialization).
// vmcnt(6) steady-state: allows B(t+1)[4] + A-stage(t+2)[2] in flight, forces
// A-stage(t+1) (and all older) complete.
// EPI 0 (QKV): q -> feature map -> Qh[bh][n][dk]; k -> feature map ->
//              Kt[bh][dk][n]; v -> Vt[bh][dv][n].  EPI 1: +bias -> fp32 out.

#define STAGE_A(BUF, KT) do {                                                        \
    _Pragma("unroll")                                                                \
    for (int j_ = 0; j_ < 2; ++j_)                                                   \
        gload_lds16(gA[j_] + (KT) * 32, (char*)lds + (BUF) * 16384 + lbase[j_]);     \
} while (0)

#define TILEB(KT, CUR, NXT, BCUR, BNXT, DOB, DOSTAGE, VMSTR) do {                    \
    if (DOB) {                                                                       \
        _Pragma("unroll")                                                            \
        for (int n_ = 0; n_ < 4; ++n_)                                               \
            BNXT[n_] = *(const f16x8*)(gBF[n_] + ((KT) + 1) * 32);                   \
    }                                                                                \
    if (DOSTAGE) STAGE_A(NXT, (KT) + 2);                                             \
    const char* Ab_ = (const char*)lds + (CUR) * 16384 + aoff;                       \
    f16x8 af_[8];                                                                    \
    _Pragma("unroll")                                                                \
    for (int m_ = 0; m_ < 8; ++m_) af_[m_] = *(const f16x8*)(Ab_ + m_ * 1024);       \
    __builtin_amdgcn_s_setprio(1);                                                   \
    _Pragma("unroll")                                                                \
    for (int m_ = 0; m_ < 8; ++m_)                                                   \
    _Pragma("unroll")                                                                \
    for (int n_ = 0; n_ < 4; ++n_)                                                   \
        acc[m_][n_] = __builtin_amdgcn_mfma_f32_16x16x32_f16(af_[m_], BCUR[n_],      \
                                                             acc[m_][n_], 0, 0, 0); \
    __builtin_amdgcn_s_setprio(0);                                                   \
    asm volatile("s_waitcnt " VMSTR ::: "memory");                                   \
    __builtin_amdgcn_s_barrier();                                                    \
    __builtin_amdgcn_sched_barrier(0);                                               \
} while (0)

template<int EPI>
__global__ __launch_bounds__(512, 2)
void gemmBD(const _Float16* __restrict__ A, const _Float16* __restrict__ Bm,
            void* __restrict__ Cout, _Float16* __restrict__ Kt,
            _Float16* __restrict__ Vt, const float* __restrict__ bias,
            const int Ncols, const int gx)
{
    __shared__ _Float16 lds[36864];   // 72 KB: 3 x 16KB A-bufs; epilogue overlay

    const int tid  = threadIdx.x;
    const int lane = tid & 63;
    const int wid  = tid >> 6;           // 0..7
    const int wm   = wid >> 2;           // 0..1 : 128-row half
    const int wn   = wid & 3;            // 0..3 : 64-col quarter

    const int nwg = gridDim.x;
    const int wg  = blockIdx.x;
    const int sw  = (wg & 7) * (nwg >> 3) + (wg >> 3);
    const int by  = sw / gx, bx = sw - by * gx;
    const int brow = by << 8, bcol = bx << 8;

    // A staging addresses (2 insts x 8KB, pre-swizzled global source)
    const _Float16* gA[2]; int lbase[2];
#pragma unroll
    for (int j = 0; j < 2; ++j) {
        int pos = ((wid * 2 + j) << 10) + (lane << 4);
        int r   = pos >> 6;
        int c8  = ((pos >> 4) & 3) ^ ((r >> 1) & 3);
        gA[j] = A + (size_t)(brow + r) * 1024 + c8 * 8;
        lbase[j] = (wid * 2 + j) << 10;
    }

    const int l15 = lane & 15, q = lane >> 4;
    const int swz  = ((q ^ ((l15 >> 1) & 3)) << 4);
    const int aoff = (wm * 128 + l15) * 64 + swz;

    // B-fragment global pointers (direct from L2-hot weight matrix)
    const _Float16* gBF[4];
#pragma unroll
    for (int n = 0; n < 4; ++n)
        gBF[n] = Bm + (size_t)(bcol + wn * 64 + n * 16 + l15) * 1024 + q * 8;

    f32x4 acc[8][4] = {};
    f16x8 bb0[4], bb1[4];

    // prologue (order pinned so vmcnt counting holds):
    // A(0)[2] | B(0)[4] | A(1)[2]  -> vmcnt(6) forces A(0) done.
    STAGE_A(0, 0);
    __builtin_amdgcn_sched_barrier(0);
#pragma unroll
    for (int n = 0; n < 4; ++n) bb0[n] = *(const f16x8*)(gBF[n]);
    __builtin_amdgcn_sched_barrier(0);
    STAGE_A(1, 1);
    asm volatile("s_waitcnt vmcnt(6)" ::: "memory");
    __builtin_amdgcn_s_barrier();
    __builtin_amdgcn_sched_barrier(0);

#pragma unroll 1
    for (int tt = 0; tt < 30; tt += 6) {
        TILEB(tt + 0, 0, 2, bb0, bb1, 1, 1, "vmcnt(6)");
        TILEB(tt + 1, 1, 0, bb1, bb0, 1, 1, "vmcnt(6)");
        TILEB(tt + 2, 2, 1, bb0, bb1, 1, 1, "vmcnt(6)");
        TILEB(tt + 3, 0, 2, bb1, bb0, 1, 1, "vmcnt(6)");
        TILEB(tt + 4, 1, 0, bb0, bb1, 1, 1, "vmcnt(6)");
        TILEB(tt + 5, 2, 1, bb1, bb0, 1, 1, "vmcnt(6)");
    }
    TILEB(30, 0, 2, bb0, bb1, 1, 0, "vmcnt(4)");
    TILEB(31, 1, 0, bb1, bb0, 0, 0, "vmcnt(0)");

    // ---------------- epilogue (R8 layout) ----------------
    if (EPI == 0) {
        const int sec = bcol >> 10;          // 0=q, 1=k, 2=v
        const bool feat = (sec < 2);
        if (feat) {
#pragma unroll
            for (int m = 0; m < 8; ++m)
#pragma unroll
                for (int r = 0; r < 4; ++r) {
                    float u[4]; float ssum = 0.f;
#pragma unroll
                    for (int n = 0; n < 4; ++n) {
                        float uu = fmaxf(acc[m][n][r], 0.f) + EPSF;
                        float c = uu * uu * uu;
                        u[n] = c; ssum += c;
                    }
                    ssum += __shfl_xor(ssum, 1, 16);
                    ssum += __shfl_xor(ssum, 2, 16);
                    ssum += __shfl_xor(ssum, 4, 16);
                    ssum += __shfl_xor(ssum, 8, 16);
                    float inv = 1.0f / ssum;
#pragma unroll
                    for (int n = 0; n < 4; ++n) acc[m][n][r] = u[n] * inv;
                }
        }
        if (sec == 0) {
            _Float16* Qh = (_Float16*)Cout;
            const int b  = brow >> 12;
            const int h  = (bcol >> 6) + wn;
            const size_t qb = (size_t)(b * 16 + h) * 4096;
            const int n0 = (brow & 4095) + wm * 128;
#pragma unroll
            for (int m = 0; m < 8; ++m) {
                int nr = n0 + m * 16 + q * 4;
#pragma unroll
                for (int r = 0; r < 4; ++r) {
                    size_t base = (qb + nr + r) * 64 + l15;
#pragma unroll
                    for (int n = 0; n < 4; ++n)
                        Qh[base + n * 16] = (_Float16)acc[m][n][r];
                }
            }
        } else {
            _Float16* T = (sec == 1) ? Kt : Vt;
            const int b   = brow >> 12;
            const int hb  = ((bcol & 1023) >> 6) + wn;
            const int bh  = b * 16 + hb;
            const int n0  = (brow & 4095) + wm * 128;
            char* st = (char*)lds + wid * 8704;       // 64 dk x 68 tok fp16
#pragma unroll
            for (int c2 = 0; c2 < 2; ++c2) {
#pragma unroll
                for (int m = 0; m < 4; ++m) {
                    int mm = c2 * 4 + m;
                    int tokc = m * 16 + q * 4;
#pragma unroll
                    for (int n = 0; n < 4; ++n) {
                        short4 pk;
                        pk.x = __builtin_bit_cast(short, (_Float16)acc[mm][n][0]);
                        pk.y = __builtin_bit_cast(short, (_Float16)acc[mm][n][1]);
                        pk.z = __builtin_bit_cast(short, (_Float16)acc[mm][n][2]);
                        pk.w = __builtin_bit_cast(short, (_Float16)acc[mm][n][3]);
                        int dk = n * 16 + l15;
                        *(short4*)(st + dk * 136 + tokc * 2) = pk;
                    }
                }
#pragma unroll
                for (int it = 0; it < 16; ++it) {
                    int dk = it * 4 + q;
                    short4 v4 = *(const short4*)(st + dk * 136 + l15 * 8);
                    *(short4*)(T + ((size_t)(bh * 64 + dk)) * 4096 + n0 + c2 * 64 + l15 * 4) = v4;
                }
            }
        }
    } else {
        float* Oc = (float*)Cout;
        const int colb = bcol + wn * 64 + l15;
#pragma unroll
        for (int m = 0; m < 8; ++m) {
            int rb = brow + wm * 128 + m * 16 + q * 4;
#pragma unroll
            for (int r = 0; r < 4; ++r) {
                size_t base = (size_t)(rb + r) * Ncols + colb;
#pragma unroll
                for (int n = 0; n < 4; ++n)
                    Oc[base + n * 16] = acc[m][n][r] + bias[colb + n * 16];
            }
        }
    }
}

// ---------------------------------------------------------------------------
// Partial kvT per (bh, kseg) + ksum partials
__global__ __launch_bounds__(256)
void kv_mfma(const _Float16* __restrict__ Kt, const _Float16* __restrict__ Vt,
             float* __restrict__ kvp, float* __restrict__ ksump)
{
    __shared__ float red[4][64][64];
    __shared__ float ksr[4][64];
    int bx = blockIdx.x;                 // 0..255
    int bh = bx >> 2, kseg = bx & 3;
    int tid = threadIdx.x;
    int w = tid >> 6, lane = tid & 63, p = lane & 15, q = lane >> 4;
    const _Float16* Vb = Vt + (size_t)bh * 64 * 4096;
    const _Float16* Kb = Kt + (size_t)bh * 64 * 4096;
    f32x4 acc[4][4] = {};
    float ksp[4] = {0.f, 0.f, 0.f, 0.f};
    int kbase = kseg * 1024 + w * 256 + q * 8;
#pragma unroll 1
    for (int ks = 0; ks < 8; ++ks) {
        int kb = kbase + ks * 32;
        f16x8 af[4], bf[4];
#pragma unroll
        for (int m = 0; m < 4; ++m)
            af[m] = *(const f16x8*)(Vb + (size_t)(m * 16 + p) * 4096 + kb);
#pragma unroll
        for (int n = 0; n < 4; ++n) {
            bf[n] = *(const f16x8*)(Kb + (size_t)(n * 16 + p) * 4096 + kb);
#pragma unroll
            for (int j = 0; j < 8; ++j) ksp[n] += (float)bf[n][j];
        }
#pragma unroll
        for (int m = 0; m < 4; ++m)
#pragma unroll
            for (int n = 0; n < 4; ++n)
                acc[m][n] = __builtin_amdgcn_mfma_f32_16x16x32_f16(
                    af[m], bf[n], acc[m][n], 0, 0, 0);
    }
#pragma unroll
    for (int n = 0; n < 4; ++n) {
        ksp[n] += __shfl_xor(ksp[n], 16);
        ksp[n] += __shfl_xor(ksp[n], 32);
    }
    if (q == 0)
#pragma unroll
        for (int n = 0; n < 4; ++n) ksr[w][n * 16 + p] = ksp[n];
#pragma unroll
    for (int m = 0; m < 4; ++m)
#pragma unroll
        for (int n = 0; n < 4; ++n)
            *(f32x4*)&red[w][n * 16 + p][m * 16 + q * 4] = acc[m][n];
    __syncthreads();
    int dv = tid & 63, dkb = (tid >> 6) * 16;
    float* ko = kvp + ((size_t)(kseg * 64 + bh)) * 4096;
    f32x4 o[4];
#pragma unroll
    for (int i = 0; i < 16; ++i) {
        float s = red[0][dkb + i][dv] + red[1][dkb + i][dv]
                + red[2][dkb + i][dv] + red[3][dkb + i][dv];
        o[i >> 2][i & 3] = s;
    }
#pragma unroll
    for (int i = 0; i < 4; ++i)
        *(f32x4*)(ko + dv * 64 + dkb + i * 4) = o[i];
    if (tid < 64)
        ksump[(size_t)(kseg * 64 + bh) * 64 + tid] =
            ksr[0][tid] + ksr[1][tid] + ksr[2][tid] + ksr[3][tid];
}

// ---------------------------------------------------------------------------
// Fold partials into kvT [bh][80][64]: rows 0-63 kv, row 64 ksum, 65-79 zero
__global__ __launch_bounds__(256)
void kv_reduce(const float* __restrict__ kvp, const float* __restrict__ ksump,
               _Float16* __restrict__ kvT)
{
    int idx = blockIdx.x * 256 + threadIdx.x;
    int col = idx & 63;
    int t = idx >> 6;
    int bh = t / 80;
    int row = t - bh * 80;
    float s = 0.f;
    if (row < 64) {
        int src = bh * 4096 + row * 64 + col;
        s = kvp[src] + kvp[262144 + src] + kvp[2 * 262144 + src] + kvp[3 * 262144 + src];
    } else if (row == 64) {
        int src = bh * 64 + col;
        s = ksump[src] + ksump[4096 + src] + ksump[2 * 4096 + src] + ksump[3 * 4096 + src];
    }
    kvT[idx] = (_Float16)s;
}

// ---------------------------------------------------------------------------
// Fused attention-out + depthwise conv + residual -> yf (fp16)
__global__ __launch_bounds__(256)
void attn_conv(const _Float16* __restrict__ Qh, const _Float16* __restrict__ kvT,
               const float* __restrict__ wdwc, const float* __restrict__ bdwc,
               _Float16* __restrict__ yf)
{
    __shared__ _Float16 ybuf[258][68];
    int blk = blockIdx.x;
    int b = blk >> 8, h = (blk >> 4) & 15, chunk = blk & 15;
    int bh = b * 16 + h;
    int tid = threadIdx.x, w = tid >> 6, lane = tid & 63, p = lane & 15, q = lane >> 4;
    const _Float16* kvb = kvT + (size_t)bh * (80 * 64);
    const _Float16* Qb  = Qh + (size_t)bh * 4096 * 64;
    f16x8 bf[2][5];
#pragma unroll
    for (int kst = 0; kst < 2; ++kst)
#pragma unroll
        for (int n = 0; n < 5; ++n)
            bf[kst][n] = *(const f16x8*)(kvb + (n * 16 + p) * 64 + kst * 32 + q * 8);

    int tok0 = chunk * 256 + w * 64;

    f32x4 acc[4][5] = {};
#pragma unroll
    for (int kst = 0; kst < 2; ++kst) {
        f16x8 af[4];
#pragma unroll
        for (int m = 0; m < 4; ++m)
            af[m] = *(const f16x8*)(Qb + (size_t)(tok0 + m * 16 + p) * 64 + kst * 32 + q * 8);
#pragma unroll
        for (int m = 0; m < 4; ++m)
#pragma unroll
            for (int n = 0; n < 5; ++n)
                acc[m][n] = __builtin_amdgcn_mfma_f32_16x16x32_f16(
                    af[m], bf[kst][n], acc[m][n], 0, 0, 0);
    }
#pragma unroll
    for (int m = 0; m < 4; ++m)
#pragma unroll
        for (int r = 0; r < 4; ++r) {
            float sz = __shfl(acc[m][4][r], lane & 48);
            float zz = 1.0f / (sz + EPSF);
            int row = 1 + w * 64 + m * 16 + q * 4 + r;
#pragma unroll
            for (int n = 0; n < 4; ++n)
                ybuf[row][n * 16 + p] = (_Float16)(acc[m][n][r] * zz);
        }
    if (w == 0 || w == 3) {
        bool lo = (w == 0);
        bool live = lo ? (chunk > 0) : (chunk < 15);
        float val = 0.f;
        if (live) {
            int t = lo ? (chunk * 256 - 1) : (chunk * 256 + 256);
            float sd = 0.f, sz = 0.f;
#pragma unroll
            for (int i = 0; i < 8; ++i) {
                f16x8 qq = *(const f16x8*)(Qb + (size_t)t * 64 + i * 8);
                f16x8 kk = *(const f16x8*)(kvb + lane * 64 + i * 8);
                f16x8 ks = *(const f16x8*)(kvb + 64 * 64 + i * 8);
#pragma unroll
                for (int j = 0; j < 8; ++j) {
                    sd += (float)qq[j] * (float)kk[j];
                    sz += (float)qq[j] * (float)ks[j];
                }
            }
            val = sd / (sz + EPSF);
        }
        ybuf[lo ? 0 : 257][lane] = (_Float16)val;
    }
    __syncthreads();
    int dv = lane;
    int c = h * 64 + dv;
    float w0 = wdwc[c * 3 + 0], w1 = wdwc[c * 3 + 1], w2 = wdwc[c * 3 + 2];
    float bb = bdwc[c];
#pragma unroll 4
    for (int it = 0; it < 64; ++it) {
        int tok = it * 4 + w;
        float ym = (float)ybuf[tok][dv];
        float yc = (float)ybuf[tok + 1][dv];
        float yp = (float)ybuf[tok + 2][dv];
        float val = yc + w0 * ym + w1 * yc + w2 * yp + bb;
        yf[((size_t)(b * 4096 + chunk * 256 + tok)) * 1024 + c] = (_Float16)val;
    }
}

// ---------------------------------------------------------------------------
extern "C" void kernel_launch(void* const* d_in, const int* in_sizes, int n_in,
                              void* d_out, int out_size, void* d_ws, size_t ws_size,
                              hipStream_t stream)
{
    const float* x      = (const float*)d_in[0];
    const float* w_qkv  = (const float*)d_in[1];
    const float* w_proj = (const float*)d_in[2];
    const float* b_proj = (const float*)d_in[3];
    const float* w_dwc  = (const float*)d_in[4];
    const float* b_dwc  = (const float*)d_in[5];

    char* p = (char*)d_ws;
    _Float16* xf   = (_Float16*)p;  p += (size_t)MM * CC * 2;
    _Float16* wqf  = (_Float16*)p;  p += (size_t)3 * CC * CC * 2;
    _Float16* wpf  = (_Float16*)p;  p += (size_t)CC * CC * 2;
    _Float16* Qh   = (_Float16*)p;  p += (size_t)MM * CC * 2;
    _Float16* Kt   = (_Float16*)p;  p += (size_t)64 * 64 * NN * 2;
    _Float16* Vt   = (_Float16*)p;  p += (size_t)64 * 64 * NN * 2;
    float*    kvp  = (float*)p;     p += (size_t)4 * 64 * 4096 * 4;
    float*    ksump= (float*)p;     p += (size_t)4 * 64 * 64 * 4;
    _Float16* kvT  = (_Float16*)p;  p += (size_t)64 * 80 * 64 * 2;
    _Float16* yf   = (_Float16*)p;  p += (size_t)MM * CC * 2;

    // 1. inputs to fp16
    tofp16_all<<<20480, 256, 0, stream>>>(x, w_qkv, w_proj, xf, wqf, wpf);

    // 2. QKV GEMM (B direct-from-L2), feature-map epilogue
    gemmBD<0><<<dim3(12 * 64), 512, 0, stream>>>(
        xf, wqf, (void*)Qh, Kt, Vt, nullptr, 3072, 12);

    // 3. kv partials + fold
    kv_mfma<<<256, 256, 0, stream>>>(Kt, Vt, kvp, ksump);
    kv_reduce<<<1280, 256, 0, stream>>>(kvp, ksump, kvT);

    // 4. attention output + depthwise conv -> yf
    attn_conv<<<BB * HH * 16, 256, 0, stream>>>(Qh, kvT, w_dwc, b_dwc, yf);

    // 5. output projection + bias (B direct-from-L2)
    gemmBD<1><<<dim3(4 * 64), 512, 0, stream>>>(
        yf, wpf, d_out, nullptr, nullptr, b_proj, 1024, 4);
}

// Round 14
// 218.655 us; speedup vs baseline: 1.2547x; 1.2547x over previous
//
#include <hip/hip_runtime.h>
#include <hip/hip_bf16.h>

// Problem constants: B=4, N=4096, C=1024, H=16, d=64
#define BB 4
#define NN 4096
#define CC 1024
#define HH 16
#define MM (BB*NN)          // 16384 token rows
#define EPSF 1e-6f

typedef _Float16 f16x8 __attribute__((ext_vector_type(8)));
typedef float f32x4 __attribute__((ext_vector_type(4)));

__device__ __forceinline__ void gload_lds16(const void* g, void* l) {
    __builtin_amdgcn_global_load_lds(
        (const __attribute__((address_space(1))) void*)g,
        (__attribute__((address_space(3))) void*)l, 16, 0, 0);
}

// ---------------------------------------------------------------------------
// fused fp32 -> fp16 conversion for x, w_qkv, w_proj (one launch)
// quads: x 4194304, w_qkv 786432, w_proj 262144 ; total 5242880
__global__ __launch_bounds__(256)
void tofp16_all(const float* __restrict__ x, const float* __restrict__ wq,
                const float* __restrict__ wp, _Float16* __restrict__ xf,
                _Float16* __restrict__ wqf, _Float16* __restrict__ wpf)
{
    int i = blockIdx.x * 256 + threadIdx.x;
    const float* src; _Float16* dst; int off;
    if (i < 4194304)      { src = x;  dst = xf;  off = 0; }
    else if (i < 4980736) { src = wq; dst = wqf; off = 4194304; }
    else                  { src = wp; dst = wpf; off = 4980736; }
    int j = i - off;
    float4 f = ((const float4*)src)[j];
    short4 pk;
    pk.x = __builtin_bit_cast(short, (_Float16)f.x);
    pk.y = __builtin_bit_cast(short, (_Float16)f.y);
    pk.z = __builtin_bit_cast(short, (_Float16)f.z);
    pk.w = __builtin_bit_cast(short, (_Float16)f.w);
    ((short4*)dst)[j] = pk;
}

// ---------------------------------------------------------------------------
// 256x256-tile fp16 MFMA GEMM, BK=32, 8 waves (2Mx4N), 3 LDS buffers,
// stage-2-ahead with counted vmcnt(4), one barrier per K-tile.  (R5-proven.)
// EPI 0 (QKV): q cols -> feature map -> Qh[bh][n][dk] (head-major);
//              k -> feature map -> transpose -> Kt[bh][dk][n];
//              v -> transpose -> Vt[bh][dv][n].
// EPI 1 (proj): +bias -> fp32 out.

#define STAGE(BUF, KT) do {                                                          \
    _Pragma("unroll")                                                                \
    for (int j_ = 0; j_ < 2; ++j_) {                                                 \
        gload_lds16(gA[j_] + (KT) * 32, (char*)lds + (BUF) * 32768 + lbase[j_]);     \
        gload_lds16(gB[j_] + (KT) * 32, (char*)lds + (BUF) * 32768 + 16384 + lbase[j_]); \
    } } while (0)

#define TILE(KT, CUR, NXT, DOSTAGE, VMSTR) do {                                      \
    if (DOSTAGE) STAGE(NXT, (KT) + 2);                                               \
    const char* Ab_ = (const char*)lds + (CUR) * 32768 + aoff;                       \
    const char* Bb_ = (const char*)lds + (CUR) * 32768 + 16384 + boff;               \
    f16x8 af_[8], bf_[4];                                                            \
    _Pragma("unroll")                                                                \
    for (int m_ = 0; m_ < 8; ++m_) af_[m_] = *(const f16x8*)(Ab_ + m_ * 1024);       \
    _Pragma("unroll")                                                                \
    for (int n_ = 0; n_ < 4; ++n_) bf_[n_] = *(const f16x8*)(Bb_ + n_ * 1024);       \
    __builtin_amdgcn_s_setprio(1);                                                   \
    _Pragma("unroll")                                                                \
    for (int m_ = 0; m_ < 8; ++m_)                                                   \
    _Pragma("unroll")                                                                \
    for (int n_ = 0; n_ < 4; ++n_)                                                   \
        acc[m_][n_] = __builtin_amdgcn_mfma_f32_16x16x32_f16(af_[m_], bf_[n_],       \
                                                             acc[m_][n_], 0, 0, 0); \
    __builtin_amdgcn_s_setprio(0);                                                   \
    asm volatile("s_waitcnt " VMSTR ::: "memory");                                   \
    __builtin_amdgcn_s_barrier();                                                    \
    __builtin_amdgcn_sched_barrier(0);                                               \
} while (0)

template<int EPI>
__global__ __launch_bounds__(512, 2)
void gemm256(const _Float16* __restrict__ A, const _Float16* __restrict__ Bm,
             void* __restrict__ Cout, _Float16* __restrict__ Kt,
             _Float16* __restrict__ Vt, const float* __restrict__ bias,
             const int Ncols, const int gx)
{
    __shared__ _Float16 lds[3 * 16384];   // 96 KB

    const int tid  = threadIdx.x;
    const int lane = tid & 63;
    const int wid  = tid >> 6;           // 0..7
    const int wm   = wid >> 2;           // 0..1 : 128-row half
    const int wn   = wid & 3;            // 0..3 : 64-col quarter

    const int nwg = gridDim.x;
    const int wg  = blockIdx.x;
    const int sw  = (wg & 7) * (nwg >> 3) + (wg >> 3);
    const int by  = sw / gx, bx = sw - by * gx;
    const int brow = by << 8, bcol = bx << 8;

    const _Float16* gA[2]; const _Float16* gB[2]; int lbase[2];
#pragma unroll
    for (int j = 0; j < 2; ++j) {
        int pos = ((wid * 2 + j) << 10) + (lane << 4);
        int r   = pos >> 6;
        int c8  = ((pos >> 4) & 3) ^ ((r >> 1) & 3);
        gA[j] = A  + (size_t)(brow + r) * 1024 + c8 * 8;
        gB[j] = Bm + (size_t)(bcol + r) * 1024 + c8 * 8;
        lbase[j] = (wid * 2 + j) << 10;
    }

    const int swz  = (((lane >> 4) ^ ((lane >> 1) & 3)) << 4);
    const int aoff = (wm * 128 + (lane & 15)) * 64 + swz;
    const int boff = (wn * 64  + (lane & 15)) * 64 + swz;

    f32x4 acc[8][4] = {};

    STAGE(0, 0);
    STAGE(1, 1);
    asm volatile("s_waitcnt vmcnt(4)" ::: "memory");
    __builtin_amdgcn_s_barrier();
    __builtin_amdgcn_sched_barrier(0);

#pragma unroll 1
    for (int tt = 0; tt < 30; tt += 3) {
        TILE(tt,     0, 2, 1, "vmcnt(4)");
        TILE(tt + 1, 1, 0, 1, "vmcnt(4)");
        TILE(tt + 2, 2, 1, 1, "vmcnt(4)");
    }
    TILE(30, 0, 2, 0, "vmcnt(0)");
    TILE(31, 1, 0, 0, "vmcnt(0)");

    if (EPI == 0) {
        const int sec = bcol >> 10;          // 0=q, 1=k, 2=v
        const bool feat = (sec < 2);
        if (feat) {
#pragma unroll
            for (int m = 0; m < 8; ++m)
#pragma unroll
                for (int r = 0; r < 4; ++r) {
                    float u[4]; float ssum = 0.f;
#pragma unroll
                    for (int n = 0; n < 4; ++n) {
                        float uu = fmaxf(acc[m][n][r], 0.f) + EPSF;
                        float c = uu * uu * uu;
                        u[n] = c; ssum += c;
                    }
                    ssum += __shfl_xor(ssum, 1, 16);
                    ssum += __shfl_xor(ssum, 2, 16);
                    ssum += __shfl_xor(ssum, 4, 16);
                    ssum += __shfl_xor(ssum, 8, 16);
                    float inv = 1.0f / ssum;
#pragma unroll
                    for (int n = 0; n < 4; ++n) acc[m][n][r] = u[n] * inv;
                }
        }
        if (sec == 0) {
            // head-major store: Qh[bh][n][dk]
            _Float16* Qh = (_Float16*)Cout;
            const int b  = brow >> 12;
            const int h  = (bcol >> 6) + wn;
            const size_t qb = (size_t)(b * 16 + h) * 4096;
            const int n0 = (brow & 4095) + wm * 128;
            const int l15 = lane & 15, q = lane >> 4;
#pragma unroll
            for (int m = 0; m < 8; ++m) {
                int nr = n0 + m * 16 + q * 4;
#pragma unroll
                for (int r = 0; r < 4; ++r) {
                    size_t base = (qb + nr + r) * 64 + l15;
#pragma unroll
                    for (int n = 0; n < 4; ++n)
                        Qh[base + n * 16] = (_Float16)acc[m][n][r];
                }
            }
        } else {
            _Float16* T = (sec == 1) ? Kt : Vt;
            const int b   = brow >> 12;
            const int hb  = ((bcol & 1023) >> 6) + wn;
            const int bh  = b * 16 + hb;
            const int n0  = (brow & 4095) + wm * 128;
            char* st = (char*)lds + wid * 8704;       // 64 dk x 68 tok fp16
            const int p = lane & 15, q2 = lane >> 4;
#pragma unroll
            for (int c2 = 0; c2 < 2; ++c2) {
#pragma unroll
                for (int m = 0; m < 4; ++m) {
                    int mm = c2 * 4 + m;
                    int tokc = m * 16 + q2 * 4;
#pragma unroll
                    for (int n = 0; n < 4; ++n) {
                        short4 pk;
                        pk.x = __builtin_bit_cast(short, (_Float16)acc[mm][n][0]);
                        pk.y = __builtin_bit_cast(short, (_Float16)acc[mm][n][1]);
                        pk.z = __builtin_bit_cast(short, (_Float16)acc[mm][n][2]);
                        pk.w = __builtin_bit_cast(short, (_Float16)acc[mm][n][3]);
                        int dk = n * 16 + p;
                        *(short4*)(st + dk * 136 + tokc * 2) = pk;
                    }
                }
#pragma unroll
                for (int it = 0; it < 16; ++it) {
                    int dk = it * 4 + q2;
                    short4 v4 = *(const short4*)(st + dk * 136 + p * 8);
                    *(short4*)(T + ((size_t)(bh * 64 + dk)) * 4096 + n0 + c2 * 64 + p * 4) = v4;
                }
            }
        }
    } else {
        float* Oc = (float*)Cout;
        const int colb = bcol + wn * 64 + (lane & 15);
#pragma unroll
        for (int m = 0; m < 8; ++m) {
            int rb = brow + wm * 128 + m * 16 + (lane >> 4) * 4;
#pragma unroll
            for (int r = 0; r < 4; ++r) {
                size_t base = (size_t)(rb + r) * Ncols + colb;
#pragma unroll
                for (int n = 0; n < 4; ++n)
                    Oc[base + n * 16] = acc[m][n][r] + bias[colb + n * 16];
            }
        }
    }
}

// ---------------------------------------------------------------------------
// Partial kvT: per (bh, kseg): kvp[kseg][bh][dv][dk] = sum_{n in seg} Vt[dv][n]*Kt[dk][n]
// ksump[kseg][bh][dk] = sum_{n in seg} Kt[dk][n]
__global__ __launch_bounds__(256)
void kv_mfma(const _Float16* __restrict__ Kt, const _Float16* __restrict__ Vt,
             float* __restrict__ kvp, float* __restrict__ ksump)
{
    __shared__ float red[4][64][64];
    __shared__ float ksr[4][64];
    int bx = blockIdx.x;                 // 0..255
    int bh = bx >> 2, kseg = bx & 3;
    int tid = threadIdx.x;
    int w = tid >> 6, lane = tid & 63, p = lane & 15, q = lane >> 4;
    const _Float16* Vb = Vt + (size_t)bh * 64 * 4096;
    const _Float16* Kb = Kt + (size_t)bh * 64 * 4096;
    f32x4 acc[4][4] = {};
    float ksp[4] = {0.f, 0.f, 0.f, 0.f};
    int kbase = kseg * 1024 + w * 256 + q * 8;
#pragma unroll 1
    for (int ks = 0; ks < 8; ++ks) {
        int kb = kbase + ks * 32;
        f16x8 af[4], bf[4];
#pragma unroll
        for (int m = 0; m < 4; ++m)
            af[m] = *(const f16x8*)(Vb + (size_t)(m * 16 + p) * 4096 + kb);
#pragma unroll
        for (int n = 0; n < 4; ++n) {
            bf[n] = *(const f16x8*)(Kb + (size_t)(n * 16 + p) * 4096 + kb);
#pragma unroll
            for (int j = 0; j < 8; ++j) ksp[n] += (float)bf[n][j];
        }
#pragma unroll
        for (int m = 0; m < 4; ++m)
#pragma unroll
            for (int n = 0; n < 4; ++n)
                acc[m][n] = __builtin_amdgcn_mfma_f32_16x16x32_f16(
                    af[m], bf[n], acc[m][n], 0, 0, 0);
    }
#pragma unroll
    for (int n = 0; n < 4; ++n) {
        ksp[n] += __shfl_xor(ksp[n], 16);
        ksp[n] += __shfl_xor(ksp[n], 32);
    }
    if (q == 0)
#pragma unroll
        for (int n = 0; n < 4; ++n) ksr[w][n * 16 + p] = ksp[n];
#pragma unroll
    for (int m = 0; m < 4; ++m)
#pragma unroll
        for (int n = 0; n < 4; ++n)
            *(f32x4*)&red[w][n * 16 + p][m * 16 + q * 4] = acc[m][n];
    __syncthreads();
    int dv = tid & 63, dkb = (tid >> 6) * 16;
    float* ko = kvp + ((size_t)(kseg * 64 + bh)) * 4096;
    f32x4 o[4];
#pragma unroll
    for (int i = 0; i < 16; ++i) {
        float s = red[0][dkb + i][dv] + red[1][dkb + i][dv]
                + red[2][dkb + i][dv] + red[3][dkb + i][dv];
        o[i >> 2][i & 3] = s;
    }
#pragma unroll
    for (int i = 0; i < 4; ++i)
        *(f32x4*)(ko + dv * 64 + dkb + i * 4) = o[i];
    if (tid < 64)
        ksump[(size_t)(kseg * 64 + bh) * 64 + tid] =
            ksr[0][tid] + ksr[1][tid] + ksr[2][tid] + ksr[3][tid];
}

// ---------------------------------------------------------------------------
// Fold 4 k-segment partials into extended kvT [bh][80][64] fp16:
// rows 0-63 = kv (dv major), row 64 = ksum, rows 65-79 = 0.
__global__ __launch_bounds__(256)
void kv_reduce(const float* __restrict__ kvp, const float* __restrict__ ksump,
               _Float16* __restrict__ kvT)
{
    int idx = blockIdx.x * 256 + threadIdx.x;        // 0..327679
    int col = idx & 63;
    int t = idx >> 6;                                // 0..5119
    int bh = t / 80;
    int row = t - bh * 80;
    float s = 0.f;
    if (row < 64) {
        int src = bh * 4096 + row * 64 + col;
        s = kvp[src] + kvp[262144 + src] + kvp[2 * 262144 + src] + kvp[3 * 262144 + src];
    } else if (row == 64) {
        int src = bh * 64 + col;
        s = ksump[src] + ksump[4096 + src] + ksump[2 * 4096 + src] + ksump[3 * 4096 + src];
    }
    kvT[idx] = (_Float16)s;
}

// ---------------------------------------------------------------------------
// Fused attention-out + depthwise conv + residual -> yf (fp16)
// block = (b, h, 256-token chunk); 4 waves x 64 tokens. Q head-major.
// z fused via 5th B-fragment (kvT row 64 = ksum): acc[m][4] col 64 = q.ksum.
__global__ __launch_bounds__(256)
void attn_conv(const _Float16* __restrict__ Qh, const _Float16* __restrict__ kvT,
               const float* __restrict__ wdwc, const float* __restrict__ bdwc,
               _Float16* __restrict__ yf)
{
    __shared__ _Float16 ybuf[258][68];
    int blk = blockIdx.x;
    int b = blk >> 8, h = (blk >> 4) & 15, chunk = blk & 15;
    int bh = b * 16 + h;
    int tid = threadIdx.x, w = tid >> 6, lane = tid & 63, p = lane & 15, q = lane >> 4;
    const _Float16* kvb = kvT + (size_t)bh * (80 * 64);
    const _Float16* Qb  = Qh + (size_t)bh * 4096 * 64;
    f16x8 bf[2][5];
#pragma unroll
    for (int kst = 0; kst < 2; ++kst)
#pragma unroll
        for (int n = 0; n < 5; ++n)
            bf[kst][n] = *(const f16x8*)(kvb + (n * 16 + p) * 64 + kst * 32 + q * 8);

    int tok0 = chunk * 256 + w * 64;

    f32x4 acc[4][5] = {};
#pragma unroll
    for (int kst = 0; kst < 2; ++kst) {
        f16x8 af[4];
#pragma unroll
        for (int m = 0; m < 4; ++m)
            af[m] = *(const f16x8*)(Qb + (size_t)(tok0 + m * 16 + p) * 64 + kst * 32 + q * 8);
#pragma unroll
        for (int m = 0; m < 4; ++m)
#pragma unroll
            for (int n = 0; n < 5; ++n)
                acc[m][n] = __builtin_amdgcn_mfma_f32_16x16x32_f16(
                    af[m], bf[kst][n], acc[m][n], 0, 0, 0);
    }
#pragma unroll
    for (int m = 0; m < 4; ++m)
#pragma unroll
        for (int r = 0; r < 4; ++r) {
            float sz = __shfl(acc[m][4][r], lane & 48);   // col 64 = q.ksum for this row
            float zz = 1.0f / (sz + EPSF);
            int row = 1 + w * 64 + m * 16 + q * 4 + r;
#pragma unroll
            for (int n = 0; n < 4; ++n)
                ybuf[row][n * 16 + p] = (_Float16)(acc[m][n][r] * zz);
        }
    // halo rows (recompute attn for tokens chunk*256-1 and chunk*256+256)
    if (w == 0 || w == 3) {
        bool lo = (w == 0);
        bool live = lo ? (chunk > 0) : (chunk < 15);
        float val = 0.f;
        if (live) {
            int t = lo ? (chunk * 256 - 1) : (chunk * 256 + 256);
            float sd = 0.f, sz = 0.f;
#pragma unroll
            for (int i = 0; i < 8; ++i) {
                f16x8 qq = *(const f16x8*)(Qb + (size_t)t * 64 + i * 8);
                f16x8 kk = *(const f16x8*)(kvb + lane * 64 + i * 8);
                f16x8 ks = *(const f16x8*)(kvb + 64 * 64 + i * 8);
#pragma unroll
                for (int j = 0; j < 8; ++j) {
                    sd += (float)qq[j] * (float)kk[j];
                    sz += (float)qq[j] * (float)ks[j];
                }
            }
            val = sd / (sz + EPSF);
        }
        ybuf[lo ? 0 : 257][lane] = (_Float16)val;
    }
    __syncthreads();
    // conv + residual + write
    int dv = lane;
    int c = h * 64 + dv;
    float w0 = wdwc[c * 3 + 0], w1 = wdwc[c * 3 + 1], w2 = wdwc[c * 3 + 2];
    float bb = bdwc[c];
#pragma unroll 4
    for (int it = 0; it < 64; ++it) {
        int tok = it * 4 + w;
        float ym = (float)ybuf[tok][dv];
        float yc = (float)ybuf[tok + 1][dv];
        float yp = (float)ybuf[tok + 2][dv];
        float val = yc + w0 * ym + w1 * yc + w2 * yp + bb;
        yf[((size_t)(b * 4096 + chunk * 256 + tok)) * 1024 + c] = (_Float16)val;
    }
}

// ---------------------------------------------------------------------------
extern "C" void kernel_launch(void* const* d_in, const int* in_sizes, int n_in,
                              void* d_out, int out_size, void* d_ws, size_t ws_size,
                              hipStream_t stream)
{
    const float* x      = (const float*)d_in[0];
    const float* w_qkv  = (const float*)d_in[1];
    const float* w_proj = (const float*)d_in[2];
    const float* b_proj = (const float*)d_in[3];
    const float* w_dwc  = (const float*)d_in[4];
    const float* b_dwc  = (const float*)d_in[5];

    char* p = (char*)d_ws;
    _Float16* xf   = (_Float16*)p;  p += (size_t)MM * CC * 2;         // 33.5 MB
    _Float16* wqf  = (_Float16*)p;  p += (size_t)3 * CC * CC * 2;     // 6.3 MB
    _Float16* wpf  = (_Float16*)p;  p += (size_t)CC * CC * 2;         // 2.1 MB
    _Float16* Qh   = (_Float16*)p;  p += (size_t)MM * CC * 2;         // 33.5 MB
    _Float16* Kt   = (_Float16*)p;  p += (size_t)64 * 64 * NN * 2;    // 33.5 MB
    _Float16* Vt   = (_Float16*)p;  p += (size_t)64 * 64 * NN * 2;    // 33.5 MB
    float*    kvp  = (float*)p;     p += (size_t)4 * 64 * 4096 * 4;   // 4.2 MB
    float*    ksump= (float*)p;     p += (size_t)4 * 64 * 64 * 4;     // 64 KB
    _Float16* kvT  = (_Float16*)p;  p += (size_t)64 * 80 * 64 * 2;    // 0.64 MB
    _Float16* yf   = (_Float16*)p;  p += (size_t)MM * CC * 2;         // 33.5 MB

    // 1. inputs to fp16 (single fused launch)
    tofp16_all<<<20480, 256, 0, stream>>>(x, w_qkv, w_proj, xf, wqf, wpf);

    // 2. QKV GEMM, feature-map epilogue; q head-major, k/v transposed per head
    gemm256<0><<<dim3(12 * 64), 512, 0, stream>>>(
        xf, wqf, (void*)Qh, Kt, Vt, nullptr, 3072, 12);

    // 3. kv partials (MFMA) + fold into extended kvT (row 64 = ksum)
    kv_mfma<<<256, 256, 0, stream>>>(Kt, Vt, kvp, ksump);
    kv_reduce<<<1280, 256, 0, stream>>>(kvp, ksump, kvT);

    // 4. attention output (z fused via 5th B-frag) + depthwise conv -> yf
    attn_conv<<<BB * HH * 16, 256, 0, stream>>>(Qh, kvT, w_dwc, b_dwc, yf);

    // 5. output projection + bias
    gemm256<1><<<dim3(4 * 64), 512, 0, stream>>>(
        yf, wpf, d_out, nullptr, nullptr, b_proj, 1024, 4);
}